// Round 5
// baseline (424.699 us; speedup 1.0000x reference)
//
#include <hip/hip_runtime.h>
#include <hip/hip_fp16.h>

// GCN on MI355X. R5: per-layer FUSED aggregate+GEMM via linearity Â(hW)=(Âh)W.
// - k_aggemm: wave aggregates 16 nodes of h (padded CSR stream, 2-deep pipeline,
//   self-loops are real edges) -> 16x128 fp16 tile in LDS -> MFMA vs W -> h'.
// - CSR build: degree+rank -> single chunk-atomic scan (writes self-edges) -> fill.
// Graph: 2 memsets + 3 preproc + gemm1 + 3 aggemm + gemm2 = 10 nodes.

typedef _Float16 f16;
typedef __attribute__((ext_vector_type(8))) _Float16 f16x8;
typedef __attribute__((ext_vector_type(4))) float f32x4;

constexpr int H = 128;

// ---------------- preprocessing ----------------

// blocks [0, EB): degree histogram + per-edge rank. blocks [EB, EB+288): weight cvt.
__global__ __launch_bounds__(256) void k_degree_cvtw(const int* __restrict__ dst,
                                                     int* __restrict__ cnt,
                                                     int* __restrict__ rank, int E, int EB,
                                                     const float* __restrict__ W1,
                                                     const float* __restrict__ Wc,
                                                     const float* __restrict__ W2,
                                                     f16* __restrict__ BT1,
                                                     f16* __restrict__ BTc,
                                                     f16* __restrict__ BT2) {
    if (blockIdx.x < (unsigned)EB) {
        int e = blockIdx.x * 256 + threadIdx.x;
        if (e < E) rank[e] = atomicAdd(&cnt[dst[e]], 1);
    } else {
        int i = (blockIdx.x - EB) * 256 + threadIdx.x;
        if (i < 16384) {                       // W1: [128][128] -> BT1[c][k]
            int c = i >> 7, k = i & 127;
            BT1[i] = (f16)W1[k * 128 + c];
        } else if (i < 65536) {                // Wc: [3][128][128]
            int j = i - 16384;
            int l = j >> 14, r = j & 16383;
            int c = r >> 7, k = r & 127;
            BTc[j] = (f16)Wc[l * 16384 + k * 128 + c];
        } else if (i < 73728) {                // W2: [128][64] -> BT2[c][k]
            int j = i - 65536;
            int c = j >> 7, k = j & 127;
            BT2[j] = (f16)W2[k * 64 + c];
        }
    }
}

// Single-kernel scan: per-node padded length pd=(cnt+1+7)&~7 (self-loop included),
// block-local exscan + chunk base via one atomicAdd -> roff2[i]={off,pd}.
// Also writes the SELF-EDGE {i, 1/(deg+1)} at slot off+cnt and dis[i].
__global__ __launch_bounds__(512) void k_scanA(const int* __restrict__ cnt,
                                               int* __restrict__ gtot,
                                               int2* __restrict__ roff2,
                                               float* __restrict__ dis,
                                               unsigned long long* __restrict__ edata,
                                               int n, int n64) {
    __shared__ int sh[512];
    __shared__ int sbase;
    int t = threadIdx.x;
    int i = blockIdx.x * 512 + t;
    int c = (i < n) ? cnt[i] : 0;
    int pd = (i < n64) ? ((c + 8) & ~7) : 0;
    sh[t] = pd;
    __syncthreads();
    for (int off = 1; off < 512; off <<= 1) {
        int x = (t >= off) ? sh[t - off] : 0;
        __syncthreads();
        sh[t] += x;
        __syncthreads();
    }
    if (t == 511) sbase = atomicAdd(gtot, sh[511]);
    __syncthreads();
    int off0 = sbase + sh[t] - pd;
    if (i < n64) roff2[i] = make_int2(off0, pd);
    if (i < n) {
        float r = rsqrtf((float)(c + 1));
        dis[i] = r;
        unsigned long long sv = (unsigned long long)(unsigned)i |
                                ((unsigned long long)__float_as_uint(r * r) << 32);
        atomicExch(&edata[off0 + c], sv);     // atomic -> L2-allocating scatter
    }
}

// CSR fill via atomicExch (RMW allocates line in L2 -> scatters write-combine).
__global__ __launch_bounds__(256) void k_fill(const int* __restrict__ src,
                                              const int* __restrict__ dst,
                                              const int* __restrict__ rank,
                                              const int2* __restrict__ roff2,
                                              const float* __restrict__ dis,
                                              unsigned long long* __restrict__ edata,
                                              int E) {
    int e = blockIdx.x * 256 + threadIdx.x;
    if (e < E) {
        int d = dst[e], s = src[e];
        int pos = roff2[d].x + rank[e];
        float nm = dis[s] * dis[d];
        unsigned long long v = (unsigned long long)(unsigned)s |
                               ((unsigned long long)__float_as_uint(nm) << 32);
        atomicExch(&edata[pos], v);
    }
}

// ---------------- GEMM: fp16 MFMA, K=128, B^T in LDS ----------------
// MODE: 1 = bias+relu (fp16 out), 2 = bias (fp32 out). AF32: A is fp32.

template <int NCOLS, int MODE, bool AF32>
__global__ __launch_bounds__(256) void k_gemm16(const void* __restrict__ Av,
                                                const f16* __restrict__ BT,
                                                const float* __restrict__ bias,
                                                void* __restrict__ Cv, int n) {
    constexpr int CT = NCOLS / 16;
    constexpr int BSTR = H + 8;
    __shared__ f16 Bs[NCOLS * BSTR];

    const int tid = threadIdx.x;
    constexpr int CHUNKS = NCOLS * H / (256 * 8);
#pragma unroll
    for (int it = 0; it < CHUNKS; ++it) {
        int idx = tid + it * 256;
        int r = idx >> 4;
        int c8 = idx & 15;
        *(f16x8*)&Bs[r * BSTR + c8 * 8] = *(const f16x8*)&BT[r * H + c8 * 8];
    }
    __syncthreads();

    const int l = tid & 63;
    const int w = tid >> 6;
    const int lrow = l & 15;
    const int lk = (l >> 4) * 8;
    int arow = blockIdx.x * 64 + w * 16 + lrow;
    int arc = arow < n ? arow : n - 1;

    f16x8 a[4];
    if constexpr (AF32) {
        const float* ap = (const float*)Av + (size_t)arc * H;
#pragma unroll
        for (int ks = 0; ks < 4; ++ks) {
            float4 u = *(const float4*)&ap[ks * 32 + lk];
            float4 v = *(const float4*)&ap[ks * 32 + lk + 4];
            f16x8 t;
            t[0] = (f16)u.x; t[1] = (f16)u.y; t[2] = (f16)u.z; t[3] = (f16)u.w;
            t[4] = (f16)v.x; t[5] = (f16)v.y; t[6] = (f16)v.z; t[7] = (f16)v.w;
            a[ks] = t;
        }
    } else {
        const f16* ap = (const f16*)Av + (size_t)arc * H;
#pragma unroll
        for (int ks = 0; ks < 4; ++ks) a[ks] = *(const f16x8*)&ap[ks * 32 + lk];
    }

    f32x4 acc[CT];
#pragma unroll
    for (int ct = 0; ct < CT; ++ct) acc[ct] = (f32x4)(0.f);

#pragma unroll
    for (int ks = 0; ks < 4; ++ks) {
#pragma unroll
        for (int ct = 0; ct < CT; ++ct) {
            f16x8 b = *(const f16x8*)&Bs[(ct * 16 + lrow) * BSTR + ks * 32 + lk];
            acc[ct] = __builtin_amdgcn_mfma_f32_16x16x32_f16(a[ks], b, acc[ct], 0, 0, 0);
        }
    }

    const int rbase = blockIdx.x * 64 + w * 16 + (l >> 4) * 4;
#pragma unroll
    for (int ct = 0; ct < CT; ++ct) {
        int col = ct * 16 + lrow;
        float bv = bias[col];
#pragma unroll
        for (int r = 0; r < 4; ++r) {
            int row = rbase + r;
            if (row >= n) continue;
            float v = acc[ct][r] + bv;
            if constexpr (MODE == 1) v = fmaxf(v, 0.f);
            if constexpr (MODE == 2)
                ((float*)Cv)[(size_t)row * NCOLS + col] = v;
            else
                ((f16*)Cv)[(size_t)row * NCOLS + col] = (f16)v;
        }
    }
}

// ---------------- fused aggregate+GEMM (one conv layer) ----------------
// h' = (Â h) @ W + bias.  Block = 256 thr = 4 waves, 64 nodes.
// Each wave: aggregate its 16 nodes over the contiguous padded edge stream
// (self-loops are edges; 2-deep edata/batch pipeline, no drains), emit fp16
// rows to per-wave LDS tile, then 32 MFMAs vs W (LDS), biased fp16 epilogue.

__global__ __launch_bounds__(256) void k_aggemm(const f16* __restrict__ hin,
                                                const int2* __restrict__ roff2,
                                                const long long* __restrict__ edata,
                                                const f16* __restrict__ BT,
                                                const float* __restrict__ bias,
                                                f16* __restrict__ hout, int n) {
    constexpr int BSTR = H + 8;            // 136 halves = 272B row stride
    __shared__ f16 Bs[H * BSTR];           // 34816 B
    __shared__ f16 As[4][16 * BSTR];       // 4 x 4352 B

    const int tid = threadIdx.x;
    // stage W (B^T) -> LDS; barrier deferred until after the agg phase
#pragma unroll
    for (int it = 0; it < 8; ++it) {
        int idx = tid + it * 256;
        int r = idx >> 4, c8 = idx & 15;
        *(f16x8*)&Bs[r * BSTR + c8 * 8] = *(const f16x8*)&BT[r * H + c8 * 8];
    }

    const int l = tid & 63;
    const int w = tid >> 6;
    const int first = blockIdx.x * 64 + w * 16;

    int2 rj = roff2[first + (l & 15)];     // lane j<16: node j's {off, padlen}
    int pdv = rj.y;
    int e    = __shfl(rj.x, 0);
    int eW   = __shfl(rj.x, 15) + __shfl(rj.y, 15);
    int eend = e + __shfl(pdv, 0);

    const __half2* h2 = (const __half2*)hin;
    f16* Aw = As[w];

    float ax = 0.f, ay = 0.f;
    int j = 0;

    long long cur[8], nxt[8];
    {
        int es = __builtin_amdgcn_readfirstlane(e);
#pragma unroll
        for (int q = 0; q < 8; ++q) cur[q] = edata[es + q];
    }
    while (e < eW) {
        int en = e + 8;
        if (en < eW) {
            int es = __builtin_amdgcn_readfirstlane(en);
#pragma unroll
            for (int q = 0; q < 8; ++q) nxt[q] = edata[es + q];
        }
        float2 v[8];
#pragma unroll
        for (int q = 0; q < 8; ++q)
            v[q] = __half22float2(h2[(size_t)(unsigned)(cur[q] & 0xffffffffLL) * 64 + l]);
#pragma unroll
        for (int q = 0; q < 8; ++q) {
            float nm = __int_as_float((int)(cur[q] >> 32));
            ax = fmaf(nm, v[q].x, ax);
            ay = fmaf(nm, v[q].y, ay);
        }
#pragma unroll
        for (int q = 0; q < 8; ++q) cur[q] = nxt[q];
        e = en;
        while (e >= eend && j < 16) {      // node boundary (wave-uniform; pd>=8)
            __half2 hv = __float22half2_rn(make_float2(ax, ay));
            *(__half2*)&Aw[j * BSTR + l * 2] = hv;
            ax = 0.f; ay = 0.f;
            ++j;
            eend += __shfl(pdv, j < 16 ? j : 15);
        }
    }
    __syncthreads();                       // Bs staged (As is per-wave)

    // MFMA phase
    const int lrow = l & 15;
    const int lk = (l >> 4) * 8;
    f16x8 a[4];
#pragma unroll
    for (int ks = 0; ks < 4; ++ks)
        a[ks] = *(const f16x8*)&Aw[lrow * BSTR + ks * 32 + lk];

    f32x4 acc[8];
#pragma unroll
    for (int ct = 0; ct < 8; ++ct) acc[ct] = (f32x4)(0.f);
#pragma unroll
    for (int ks = 0; ks < 4; ++ks)
#pragma unroll
        for (int ct = 0; ct < 8; ++ct) {
            f16x8 b = *(const f16x8*)&Bs[(ct * 16 + lrow) * BSTR + ks * 32 + lk];
            acc[ct] = __builtin_amdgcn_mfma_f32_16x16x32_f16(a[ks], b, acc[ct], 0, 0, 0);
        }

    const int rbase = first + (l >> 4) * 4;
#pragma unroll
    for (int ct = 0; ct < 8; ++ct) {
        int col = ct * 16 + lrow;
        float bv = bias[col];
#pragma unroll
        for (int r = 0; r < 4; ++r) {
            int row = rbase + r;
            if (row < n) hout[(size_t)row * H + col] = (f16)(acc[ct][r] + bv);
        }
    }
}

// ---------------- launcher ----------------

extern "C" void kernel_launch(void* const* d_in, const int* in_sizes, int n_in,
                              void* d_out, int out_size, void* d_ws, size_t ws_size,
                              hipStream_t stream) {
    const float* x  = (const float*)d_in[0];
    const int*   ei = (const int*)d_in[1];
    const float* W1 = (const float*)d_in[2];
    const float* b1 = (const float*)d_in[3];
    const float* Wc = (const float*)d_in[4];
    const float* bc = (const float*)d_in[5];
    const float* W2 = (const float*)d_in[6];
    const float* b2 = (const float*)d_in[7];
    float* out = (float*)d_out;

    const int n = in_sizes[0] / H;         // 50000
    const int E = in_sizes[1] / 2;         // 800000
    const int n64 = (n + 63) & ~63;        // 50048
    const int* src = ei;
    const int* dst = ei + E;

    char* p = (char*)d_ws;
    auto alloc = [&](size_t b) -> void* {
        void* r = (void*)p;
        p += (b + 255) & ~(size_t)255;
        return r;
    };
    f16*   h    = (f16*)alloc((size_t)n64 * H * 2);
    f16*   h2   = (f16*)alloc((size_t)n64 * H * 2);
    f16*   BT1  = (f16*)alloc(16384 * 2);
    f16*   BTc  = (f16*)alloc(3 * 16384 * 2);
    f16*   BT2  = (f16*)alloc(8192 * 2);
    int*   cntg = (int*)alloc((size_t)(n + 1) * 4);   // cnt[n] + gtot
    int*   cnt  = cntg;
    int*   gtot = cntg + n;
    int*   rank = (int*)alloc((size_t)E * 4);
    int2*  roff2 = (int2*)alloc((size_t)n64 * 8);
    const size_t ecap = (size_t)E + 8 * (size_t)n64;
    unsigned long long* edata = (unsigned long long*)alloc(ecap * 8);
    float* dis  = (float*)alloc((size_t)n * 4);

    hipMemsetAsync(cntg, 0, (size_t)(n + 1) * 4, stream);
    hipMemsetAsync(edata, 0, ecap * 8, stream);       // pad slots -> (src=0, nm=0)

    const int EB = (E + 255) / 256;
    k_degree_cvtw<<<EB + 288, 256, 0, stream>>>(dst, cnt, rank, E, EB,
                                                W1, Wc, W2, BT1, BTc, BT2);
    k_scanA<<<(n64 + 511) / 512, 512, 0, stream>>>(cnt, gtot, roff2, dis, edata, n, n64);
    k_fill<<<EB, 256, 0, stream>>>(src, dst, rank, roff2, dis, edata, E);

    const int gblk = n64 / 64;             // 782
    k_gemm16<128, 1, true><<<gblk, 256, 0, stream>>>(x, BT1, b1, h, n);
    k_aggemm<<<gblk, 256, 0, stream>>>(h,  roff2, (const long long*)edata, BTc,         bc,       h2, n);
    k_aggemm<<<gblk, 256, 0, stream>>>(h2, roff2, (const long long*)edata, BTc + 16384, bc + 128, h,  n);
    k_aggemm<<<gblk, 256, 0, stream>>>(h,  roff2, (const long long*)edata, BTc + 32768, bc + 256, h2, n);
    k_gemm16<64, 2, false><<<gblk, 256, 0, stream>>>(h2, BT2, b2, out, n);
}

// Round 8
// 320.509 us; speedup vs baseline: 1.3251x; 1.3251x over previous
//
#include <hip/hip_runtime.h>
#include <hip/hip_fp16.h>

// GCN on MI355X. R6/R8: split kernels (fusion regressed: occupancy).
// - edata = 4B src (sentinel -1 = pad); norm = dis[src]*dis[dst] recomputed in agg.
// - self-loop is a CSR edge (nm = dis[i]^2 automatically); scanA writes self+pads
//   (no edata memset).
// - agg: wave/node, 8-batch stream, 2-deep prefetch, half2 regs, lean VGPR
//   for max occupancy (probe the ~2.4 TB/s L2-miss-path plateau).

typedef _Float16 f16;
typedef __attribute__((ext_vector_type(8))) _Float16 f16x8;
typedef __attribute__((ext_vector_type(4))) float f32x4;

constexpr int H = 128;

// ---------------- preprocessing ----------------

// blocks [0, EB): degree histogram + per-edge rank. blocks [EB, EB+288): weight cvt.
__global__ __launch_bounds__(256) void k_degree_cvtw(const int* __restrict__ dst,
                                                     int* __restrict__ cnt,
                                                     int* __restrict__ rank, int E, int EB,
                                                     const float* __restrict__ W1,
                                                     const float* __restrict__ Wc,
                                                     const float* __restrict__ W2,
                                                     f16* __restrict__ BT1,
                                                     f16* __restrict__ BTc,
                                                     f16* __restrict__ BT2) {
    if (blockIdx.x < (unsigned)EB) {
        int e = blockIdx.x * 256 + threadIdx.x;
        if (e < E) rank[e] = atomicAdd(&cnt[dst[e]], 1);
    } else {
        int i = (blockIdx.x - EB) * 256 + threadIdx.x;
        if (i < 16384) {                       // W1: [128][128] -> BT1[c][k]
            int c = i >> 7, k = i & 127;
            BT1[i] = (f16)W1[k * 128 + c];
        } else if (i < 65536) {                // Wc: [3][128][128]
            int j = i - 16384;
            int l = j >> 14, r = j & 16383;
            int c = r >> 7, k = r & 127;
            BTc[j] = (f16)Wc[l * 16384 + k * 128 + c];
        } else if (i < 73728) {                // W2: [128][64] -> BT2[c][k]
            int j = i - 65536;
            int c = j >> 7, k = j & 127;
            BT2[j] = (f16)W2[k * 64 + c];
        }
    }
}

// Single-kernel scan: pd = (cnt+1+7)&~7 (self-loop included), block exscan +
// chunk base via one atomicAdd. Writes dis, the self-edge (src=i), and pad
// sentinels (-1) so no edata memset is needed.
__global__ __launch_bounds__(512) void k_scanA(const int* __restrict__ cnt,
                                               int* __restrict__ gtot,
                                               int2* __restrict__ roff2,
                                               float* __restrict__ dis,
                                               int* __restrict__ edata,
                                               int n, int n64) {
    __shared__ int sh[512];
    __shared__ int sbase;
    int t = threadIdx.x;
    int i = blockIdx.x * 512 + t;
    int c = (i < n) ? cnt[i] : 0;
    int pd = (i < n64) ? ((c + 8) & ~7) : 0;
    sh[t] = pd;
    __syncthreads();
    for (int off = 1; off < 512; off <<= 1) {
        int x = (t >= off) ? sh[t - off] : 0;
        __syncthreads();
        sh[t] += x;
        __syncthreads();
    }
    if (t == 511) sbase = atomicAdd(gtot, sh[511]);
    __syncthreads();
    int off0 = sbase + sh[t] - pd;
    if (i < n64) {
        roff2[i] = make_int2(off0, pd);
        int k0 = 0;
        if (i < n) {
            dis[i] = rsqrtf((float)(c + 1));
            atomicExch(&edata[off0 + c], i);       // self edge
            k0 = c + 1;
        }
        for (int k = k0; k < pd; ++k) atomicExch(&edata[off0 + k], -1);
    }
}

// CSR fill: 4B src scatter via atomicExch (RMW allocates line in L2 -> combines).
__global__ __launch_bounds__(256) void k_fill(const int* __restrict__ src,
                                              const int* __restrict__ dst,
                                              const int* __restrict__ rank,
                                              const int2* __restrict__ roff2,
                                              int* __restrict__ edata, int E) {
    int e = blockIdx.x * 256 + threadIdx.x;
    if (e < E) {
        int d = dst[e];
        atomicExch(&edata[roff2[d].x + rank[e]], src[e]);
    }
}

// ---------------- GEMM: fp16 MFMA, K=128, B^T in LDS ----------------
// MODE: 0 = plain (fp16 out), 1 = bias+relu (fp16 out), 2 = bias (fp32 out)

template <int NCOLS, int MODE, bool AF32>
__global__ __launch_bounds__(256) void k_gemm16(const void* __restrict__ Av,
                                                const f16* __restrict__ BT,
                                                const float* __restrict__ bias,
                                                void* __restrict__ Cv, int n) {
    constexpr int CT = NCOLS / 16;
    constexpr int BSTR = H + 8;
    __shared__ f16 Bs[NCOLS * BSTR];

    const int tid = threadIdx.x;
    constexpr int CHUNKS = NCOLS * H / (256 * 8);
#pragma unroll
    for (int it = 0; it < CHUNKS; ++it) {
        int idx = tid + it * 256;
        int r = idx >> 4;
        int c8 = idx & 15;
        *(f16x8*)&Bs[r * BSTR + c8 * 8] = *(const f16x8*)&BT[r * H + c8 * 8];
    }
    __syncthreads();

    const int l = tid & 63;
    const int w = tid >> 6;
    const int lrow = l & 15;
    const int lk = (l >> 4) * 8;
    int arow = blockIdx.x * 64 + w * 16 + lrow;
    int arc = arow < n ? arow : n - 1;

    f16x8 a[4];
    if constexpr (AF32) {
        const float* ap = (const float*)Av + (size_t)arc * H;
#pragma unroll
        for (int ks = 0; ks < 4; ++ks) {
            float4 u = *(const float4*)&ap[ks * 32 + lk];
            float4 v = *(const float4*)&ap[ks * 32 + lk + 4];
            f16x8 t;
            t[0] = (f16)u.x; t[1] = (f16)u.y; t[2] = (f16)u.z; t[3] = (f16)u.w;
            t[4] = (f16)v.x; t[5] = (f16)v.y; t[6] = (f16)v.z; t[7] = (f16)v.w;
            a[ks] = t;
        }
    } else {
        const f16* ap = (const f16*)Av + (size_t)arc * H;
#pragma unroll
        for (int ks = 0; ks < 4; ++ks) a[ks] = *(const f16x8*)&ap[ks * 32 + lk];
    }

    f32x4 acc[CT];
#pragma unroll
    for (int ct = 0; ct < CT; ++ct) acc[ct] = (f32x4)(0.f);

#pragma unroll
    for (int ks = 0; ks < 4; ++ks) {
#pragma unroll
        for (int ct = 0; ct < CT; ++ct) {
            f16x8 b = *(const f16x8*)&Bs[(ct * 16 + lrow) * BSTR + ks * 32 + lk];
            acc[ct] = __builtin_amdgcn_mfma_f32_16x16x32_f16(a[ks], b, acc[ct], 0, 0, 0);
        }
    }

    const int rbase = blockIdx.x * 64 + w * 16 + (l >> 4) * 4;
#pragma unroll
    for (int ct = 0; ct < CT; ++ct) {
        int col = ct * 16 + lrow;
        float bv = 0.f;
        if constexpr (MODE != 0) bv = bias[col];
#pragma unroll
        for (int r = 0; r < 4; ++r) {
            int row = rbase + r;
            if (row >= n) continue;
            float v = acc[ct][r] + bv;
            if constexpr (MODE == 1) v = fmaxf(v, 0.f);
            if constexpr (MODE == 2)
                ((float*)Cv)[(size_t)row * NCOLS + col] = v;
            else
                ((f16*)Cv)[(size_t)row * NCOLS + col] = (f16)v;
        }
    }
}

// ---------------- aggregation: wave/node, 4B edata, lean VGPR ----------------

__global__ __launch_bounds__(512) void k_agg16(const __half2* __restrict__ hw,
                                               const int2* __restrict__ roff2,
                                               const int* __restrict__ edata,
                                               const float* __restrict__ dis,
                                               const float* __restrict__ bias,
                                               __half2* __restrict__ hout, int n) {
    const int wave = threadIdx.x >> 6;
    const int lane = threadIdx.x & 63;
    const int node = blockIdx.x * 8 + wave;      // node < n64 always

    int2 r0 = roff2[node];
    int e = r0.x;
    const int e1 = r0.x + r0.y;                  // length multiple of 8, >= 8
    const float dd = dis[node < n ? node : 0];   // garbage rows: all sentinels

    float ax = 0.f, ay = 0.f;
    int s[8], s2[8];
#pragma unroll
    for (int q = 0; q < 8; ++q) s[q] = edata[e + q];
    e += 8;

    while (true) {
        const bool more = (e < e1);
        if (more) {
#pragma unroll
            for (int q = 0; q < 8; ++q) s2[q] = edata[e + q];
        }
        __half2 v[8];
#pragma unroll
        for (int q = 0; q < 8; ++q) {
            int sc = s[q] < 0 ? 0 : s[q];        // safe addr for sentinels
            v[q] = hw[(size_t)sc * 64 + lane];
        }
        float nm[8];
#pragma unroll
        for (int q = 0; q < 8; ++q) {
            int sc = s[q] < 0 ? 0 : s[q];
            float d = dis[sc] * dd;
            nm[q] = s[q] < 0 ? 0.f : d;
        }
#pragma unroll
        for (int q = 0; q < 8; ++q) {
            float2 f = __half22float2(v[q]);
            ax = fmaf(nm[q], f.x, ax);
            ay = fmaf(nm[q], f.y, ay);
        }
        if (!more) break;
#pragma unroll
        for (int q = 0; q < 8; ++q) s[q] = s2[q];
        e += 8;
    }

    float2 b = ((const float2*)bias)[lane];
    __half2 o = __float22half2_rn(make_float2(ax + b.x, ay + b.y));
    hout[(size_t)node * 64 + lane] = o;
}

// ---------------- launcher ----------------

extern "C" void kernel_launch(void* const* d_in, const int* in_sizes, int n_in,
                              void* d_out, int out_size, void* d_ws, size_t ws_size,
                              hipStream_t stream) {
    const float* x  = (const float*)d_in[0];
    const int*   ei = (const int*)d_in[1];
    const float* W1 = (const float*)d_in[2];
    const float* b1 = (const float*)d_in[3];
    const float* Wc = (const float*)d_in[4];
    const float* bc = (const float*)d_in[5];
    const float* W2 = (const float*)d_in[6];
    const float* b2 = (const float*)d_in[7];
    float* out = (float*)d_out;

    const int n = in_sizes[0] / H;         // 50000
    const int E = in_sizes[1] / 2;         // 800000
    const int n64 = (n + 63) & ~63;        // 50048
    const int* src = ei;
    const int* dst = ei + E;

    char* p = (char*)d_ws;
    auto alloc = [&](size_t b) -> void* {
        void* r = (void*)p;
        p += (b + 255) & ~(size_t)255;
        return r;
    };
    f16*   h    = (f16*)alloc((size_t)n64 * H * 2);
    f16*   h2   = (f16*)alloc((size_t)n64 * H * 2);
    f16*   BT1  = (f16*)alloc(16384 * 2);
    f16*   BTc  = (f16*)alloc(3 * 16384 * 2);
    f16*   BT2  = (f16*)alloc(8192 * 2);
    int*   cntg = (int*)alloc((size_t)(n + 1) * 4);   // cnt[n] + gtot
    int*   cnt  = cntg;
    int*   gtot = cntg + n;
    int*   rank = (int*)alloc((size_t)E * 4);
    int2*  roff2 = (int2*)alloc((size_t)n64 * 8);
    const size_t ecap = (size_t)E + 8 * (size_t)n64;  // padded capacity (ints)
    int*   edata = (int*)alloc(ecap * 4);
    float* dis  = (float*)alloc((size_t)n * 4);

    hipMemsetAsync(cntg, 0, (size_t)(n + 1) * 4, stream);

    const int EB = (E + 255) / 256;
    k_degree_cvtw<<<EB + 288, 256, 0, stream>>>(dst, cnt, rank, E, EB,
                                                W1, Wc, W2, BT1, BTc, BT2);
    k_scanA<<<(n64 + 511) / 512, 512, 0, stream>>>(cnt, gtot, roff2, dis, edata, n, n64);
    k_fill<<<EB, 256, 0, stream>>>(src, dst, rank, roff2, edata, E);

    const int gblk = n64 / 64;             // 782
    const int ablk = n64 / 8;              // 6256
    k_gemm16<128, 1, true><<<gblk, 256, 0, stream>>>(x, BT1, b1, h, n);
    for (int l = 0; l < 3; ++l) {
        k_gemm16<128, 0, false><<<gblk, 256, 0, stream>>>(h, BTc + (size_t)l * 16384,
                                                          nullptr, h2, n);
        k_agg16<<<ablk, 512, 0, stream>>>((const __half2*)h2, roff2, edata, dis,
                                          bc + (size_t)l * H, (__half2*)h, n);
    }
    k_gemm16<64, 2, false><<<gblk, 256, 0, stream>>>(h, BT2, b2, out, n);
}